// Round 17
// baseline (361.612 us; speedup 1.0000x reference)
//
#include <hip/hip_runtime.h>

typedef float floatx16 __attribute__((ext_vector_type(16)));
typedef __bf16 bf16x8 __attribute__((ext_vector_type(8)));
using u16 = unsigned short;
using u32 = unsigned int;
using u64 = unsigned long long;

#define GLOBAL_AS __attribute__((address_space(1)))
#define LDS_AS    __attribute__((address_space(3)))

__device__ __forceinline__ u32 rne_bf16(float f) {
  u32 u = __float_as_uint(f);
  return (u + 0x7FFFu + ((u >> 16) & 1u)) >> 16;  // RNE
}

// ---------------- A: fp32 -> bf16, tile-permuted for 32x32x16 frags (R10) ----------------
__global__ __launch_bounds__(256) void cvt_x_perm(const float* __restrict__ x,
                                                  u16* __restrict__ xb, int K) {
  __shared__ u16 sm[16384];
  const int tid = threadIdx.x;
  const int Kt = K >> 6;
  const int pn = blockIdx.x / Kt, tt = blockIdx.x % Kt;
  const float* src = x + (size_t)pn * 256 * K + tt * 64;
#pragma unroll
  for (int j = 0; j < 16; ++j) {
    const int fc = j * 256 + tid;
    const int row = fc >> 4, kl4 = fc & 15;
    const float4 v = *(const float4*)(src + (size_t)row * K + kl4 * 4);
    uint2 o;
    o.x = rne_bf16(v.x) | (rne_bf16(v.y) << 16);
    o.y = rne_bf16(v.z) | (rne_bf16(v.w) << 16);
    const int gi = row >> 5, rowin = row & 31;
    const int ks = kl4 >> 2;
    const int lane = rowin + 32 * ((kl4 >> 1) & 1);
    const int e4 = (kl4 & 1) * 4;
    *(uint2*)(sm + gi * 2048 + ks * 512 + lane * 8 + e4) = o;
  }
  __syncthreads();
  u16* dst = xb + (size_t)pn * 256 * K + (size_t)tt * 16384;
#pragma unroll
  for (int j = 0; j < 8; ++j) {
    const int o = (j * 256 + tid) * 8;
    *(uint4*)(dst + o) = *(const uint4*)(sm + o);
  }
}

// ---- B: fp32 -> 2-bit codes (1=+1, 3=-1, 0=0), packed per (panel,tile) as 512 x uint2 ----
// Thread tid's uint2 covers the 32 u16 of LDS B-region [tid*32, +32): u16 #j (j=0..31)
// is frag element (ni=tid>>6, ks=(tid>>4)&3, l_loc=4*(tid&15)+(j>>3), e=j&7), i.e.
// n_loc = ni*32 + (l_loc&31), k_loc = ks*16 + (l_loc>>5)*8 + e. Bit pos: j<16 -> x bits 2j;
// j>=16 -> y bits 2(j-16). Matches the GEMM's dec4 nibble mapping exactly.
__global__ __launch_bounds__(512) void quant_w_pack2(const float* __restrict__ w,
                                                     u16* __restrict__ wb, int K) {
  __shared__ unsigned char cb[16384];  // code byte per (n_loc, k_loc): cb[n*64+k]
  const int tid = threadIdx.x;
  const int Kt = K >> 6;
  const int pn = blockIdx.x / Kt, tt = blockIdx.x % Kt;
  const float* src = w + (size_t)pn * 256 * K + tt * 64;
#pragma unroll
  for (int j = 0; j < 8; ++j) {
    const int fc = j * 512 + tid;           // float4 index in 256x64 tile
    const int row = fc >> 4, kl4 = fc & 15;
    const float4 v = *(const float4*)(src + (size_t)row * K + kl4 * 4);
    float vv[4] = {v.x, v.y, v.z, v.w};
    u32 c4 = 0;
#pragma unroll
    for (int e = 0; e < 4; ++e) {
      u32 c = (vv[e] > 0.05f) ? 1u : ((vv[e] < -0.05f) ? 3u : 0u);
      c4 |= c << (8 * e);
    }
    *(u32*)(cb + row * 64 + kl4 * 4) = c4;
  }
  __syncthreads();
  const int ni = tid >> 6, ks = (tid >> 4) & 3, lb = 4 * (tid & 15);
  u32 half[4];
#pragma unroll
  for (int g = 0; g < 4; ++g) {
    const int l_loc = lb + g;
    const int n_loc = ni * 32 + (l_loc & 31);
    const int kb = ks * 16 + (l_loc >> 5) * 8;
    const u64 b = *(const u64*)(cb + n_loc * 64 + kb);  // 8 code bytes
    u32 h = 0;
#pragma unroll
    for (int e = 0; e < 8; ++e) h |= (u32)((b >> (8 * e)) & 3u) << (2 * e);
    half[g] = h;
  }
  uint2 pk;
  pk.x = half[0] | (half[1] << 16);
  pk.y = half[2] | (half[3] << 16);
  *(uint2*)(wb + ((size_t)(pn * Kt + tt) * 512 + tid) * 4) = pk;
}

// decode 4 u32 (8 bf16) from 16 bits of a packed word starting at bit sh
__device__ __forceinline__ uint4 dec4(u32 word, int sh) {
  uint4 o;
  u32* p = (u32*)&o;
#pragma unroll
  for (int i = 0; i < 4; ++i) {
    const u32 x = (word >> (sh + 4 * i)) & 0xFu;
    const u32 lo = (x & 1u) * 0x3F80u | ((x & 2u) << 14);
    const u32 hi = ((x >> 2) & 1u) * 0x3F80u | ((x & 8u) << 12);
    p[i] = lo | (hi << 16);
  }
  return o;
}

// ---------------- R11 champion GEMM; B staged via 2-bit codes + in-tile decode ----------------
// A path / phases / barriers / MFMA / epilogue = R11 (251us). B path: P1 loads pk(t+2)
// (8B/thread, coalesced); P3/P4 decode AFTER their MFMA clusters (hides under matrix
// pipe) and ds_write_b128 into bufc's B region (B(t+2); readers at t+2; WAR safe: last
// bufc-B readers finished at P2-end barrier). Tile-end: vmcnt(2) lgkmcnt(0) -- newest 2
// = A02(t+2); A13(t+1) provably drained (pk, issued after it, was consumed by decode);
// lgkm publishes the B writes. VMEM/tile: 64 -> 36 KB (delivery-hypothesis test).
__global__ __launch_bounds__(512, 2) void gemm_bin_pk2(
    const u16* __restrict__ Ap, const u16* __restrict__ Bp,
    const float* __restrict__ bias, float* __restrict__ C,
    int M, int N, int K) {
  __shared__ u16 lds[65536];  // 2 buf x (A 16384 | B 16384) u16

  const int tid = threadIdx.x;
  const int w = tid >> 6, l = tid & 63;
  const int wr = w >> 2, wc = w & 3;

  const int nbn = N >> 8;
  int wg = blockIdx.x;
  const int nwg = gridDim.x;
  if ((nwg & 7) == 0) wg = (wg & 7) * (nwg >> 3) + (wg >> 3);  // XCD swizzle (bijective)
  const int bm = wg / nbn, bn = wg % nbn;

  const int T = K >> 6;

  const u16* const Abase = Ap + (size_t)bm * ((size_t)K << 8) + tid * 8;
  const u16* const pkbase = Bp + (size_t)bn * T * 2048 + tid * 4;  // uint2 per (tile,thread)

  const u16* const afp0 = lds + wr * 8192 + l * 8;
  const u16* const bfp0 = lds + 16384 + wc * 4096 + l * 8;
  const int bwr = 16384 + tid * 32;  // B decode-write base (u16, within buffer)

  floatx16 acc[4][2] = {};
  bf16x8 af[8], bflo[4], bfhi[4];
  uint2 pk;

#define GLOAD(gptr, u16off)                                                    \
  __builtin_amdgcn_global_load_lds((const GLOBAL_AS void*)(gptr),              \
                                   (LDS_AS void*)(lds + (u16off)), 16, 0, 0)
#define BARRIER __builtin_amdgcn_s_barrier()
#define LGKM0  do { asm volatile("s_waitcnt lgkmcnt(0)" ::: "memory");         \
                    __builtin_amdgcn_sched_barrier(0); } while (0)

  // ---- prologue: A(0)->buf0, A02(1)->buf1, pk(0),pk(1) -> decode B(0),B(1); full drain ----
  GLOAD(Abase + 0 * 4096,      0 + tid * 8);
  GLOAD(Abase + 1 * 4096,   4096 + tid * 8);
  GLOAD(Abase + 2 * 4096,   8192 + tid * 8);
  GLOAD(Abase + 3 * 4096,  12288 + tid * 8);
  if (T > 1) {
    GLOAD(Abase + 16384 + 0 * 4096, 32768 + 0 + tid * 8);
    GLOAD(Abase + 16384 + 2 * 4096, 32768 + 8192 + tid * 8);
  }
  {
    uint2 p0 = *(const uint2*)(pkbase);
    *(uint4*)(lds + bwr + 0)  = dec4(p0.x, 0);
    *(uint4*)(lds + bwr + 8)  = dec4(p0.x, 16);
    *(uint4*)(lds + bwr + 16) = dec4(p0.y, 0);
    *(uint4*)(lds + bwr + 24) = dec4(p0.y, 16);
    if (T > 1) {
      uint2 p1 = *(const uint2*)(pkbase + 2048);
      *(uint4*)(lds + 32768 + bwr + 0)  = dec4(p1.x, 0);
      *(uint4*)(lds + 32768 + bwr + 8)  = dec4(p1.x, 16);
      *(uint4*)(lds + 32768 + bwr + 16) = dec4(p1.y, 0);
      *(uint4*)(lds + 32768 + bwr + 24) = dec4(p1.y, 16);
    }
  }
  asm volatile("s_waitcnt vmcnt(0) lgkmcnt(0)" ::: "memory");
  BARRIER;

  for (int t = 0; t < T; ++t) {
    const int bufc = (t & 1) << 15;
    const int bufo = bufc ^ 32768;
    const bool st1 = (t + 1 < T);
    const bool st2 = (t + 2 < T);
    const size_t tn1 = (size_t)(t + 1) * 16384;
    const size_t tn2 = (size_t)(t + 2) * 16384;

    const u16* afp = afp0 + bufc;
    const u16* bfp = bfp0 + bufc;

    // ---- P1: af01 (8) + bflo (4); stage A13(t+1)->bufo; load pk(t+2); Q(m01,n0) ----
#pragma unroll
    for (int m = 0; m < 2; ++m)
#pragma unroll
      for (int ks = 0; ks < 4; ++ks)
        af[m * 4 + ks] = *(const bf16x8*)(afp + m * 2048 + ks * 512);
#pragma unroll
    for (int ks = 0; ks < 4; ++ks) bflo[ks] = *(const bf16x8*)(bfp + ks * 512);
    if (st1) {
      GLOAD(Abase + tn1 + 1 * 4096, bufo + 4096 + tid * 8);
      GLOAD(Abase + tn1 + 3 * 4096, bufo + 12288 + tid * 8);
    }
    if (st2) pk = *(const uint2*)(pkbase + tn2 / 8);  // (t+2)*2048 u16
    asm volatile("s_waitcnt lgkmcnt(8)" ::: "memory");
    BARRIER;
    LGKM0;
    __builtin_amdgcn_s_setprio(1);
#pragma unroll
    for (int ks = 0; ks < 4; ++ks)
#pragma unroll
      for (int m = 0; m < 2; ++m)
        acc[m][0] = __builtin_amdgcn_mfma_f32_32x32x16_bf16(
            af[m * 4 + ks], bflo[ks], acc[m][0], 0, 0, 0);
    __builtin_amdgcn_s_setprio(0);
    BARRIER;

    // ---- P2: bfhi (4); stage A02(t+2)->bufc; Q(m01,n1) ----
#pragma unroll
    for (int ks = 0; ks < 4; ++ks) bfhi[ks] = *(const bf16x8*)(bfp + 2048 + ks * 512);
    if (st2) {
      GLOAD(Abase + tn2 + 0 * 4096, bufc + 0 + tid * 8);
      GLOAD(Abase + tn2 + 2 * 4096, bufc + 8192 + tid * 8);
    }
    BARRIER;
    LGKM0;
    __builtin_amdgcn_s_setprio(1);
#pragma unroll
    for (int ks = 0; ks < 4; ++ks)
#pragma unroll
      for (int m = 0; m < 2; ++m)
        acc[m][1] = __builtin_amdgcn_mfma_f32_32x32x16_bf16(
            af[m * 4 + ks], bfhi[ks], acc[m][1], 0, 0, 0);
    __builtin_amdgcn_s_setprio(0);
    BARRIER;

    // ---- P3: af23 (8); Q(m23,n0); then decode pk.x -> B(t+2) q0,q1 (WAR-safe post-P2) ----
#pragma unroll
    for (int m = 0; m < 2; ++m)
#pragma unroll
      for (int ks = 0; ks < 4; ++ks)
        af[m * 4 + ks] = *(const bf16x8*)(afp + 4096 + m * 2048 + ks * 512);
    asm volatile("s_waitcnt lgkmcnt(4)" ::: "memory");
    BARRIER;
    LGKM0;
    __builtin_amdgcn_s_setprio(1);
#pragma unroll
    for (int ks = 0; ks < 4; ++ks)
#pragma unroll
      for (int m = 0; m < 2; ++m)
        acc[2 + m][0] = __builtin_amdgcn_mfma_f32_32x32x16_bf16(
            af[m * 4 + ks], bflo[ks], acc[2 + m][0], 0, 0, 0);
    __builtin_amdgcn_s_setprio(0);
    if (st2) {
      *(uint4*)(lds + bufc + bwr - 16384 + 16384 + 0) = dec4(pk.x, 0);   // bufc+16384+tid*32
      *(uint4*)(lds + bufc + bwr + 8) = dec4(pk.x, 16);
    }
    BARRIER;

    // ---- P4: Q(m23,n1); decode pk.y -> q2,q3; tile-end counted wait + publish ----
    __builtin_amdgcn_s_setprio(1);
#pragma unroll
    for (int ks = 0; ks < 4; ++ks)
#pragma unroll
      for (int m = 0; m < 2; ++m)
        acc[2 + m][1] = __builtin_amdgcn_mfma_f32_32x32x16_bf16(
            af[m * 4 + ks], bfhi[ks], acc[2 + m][1], 0, 0, 0);
    __builtin_amdgcn_s_setprio(0);
    if (st2) {
      *(uint4*)(lds + bufc + bwr + 16) = dec4(pk.y, 0);
      *(uint4*)(lds + bufc + bwr + 24) = dec4(pk.y, 16);
    }
    if (st1) {
      if (st2) asm volatile("s_waitcnt vmcnt(2) lgkmcnt(0)" ::: "memory");
      else     asm volatile("s_waitcnt vmcnt(0) lgkmcnt(0)" ::: "memory");
      BARRIER;
    }
  }
#undef GLOAD
#undef BARRIER
#undef LGKM0

  // ---- epilogue: C/D col=l&31, row=(q&3)+8*(q>>2)+4*(l>>5) (m74/m101-verified) ----
  const int colq = l & 31;
  const int hi4 = (l >> 5) * 4;
#pragma unroll
  for (int m = 0; m < 4; ++m) {
    const int rowb = bm * 256 + wr * 128 + m * 32 + hi4;
#pragma unroll
    for (int n = 0; n < 2; ++n) {
      const int col = bn * 256 + wc * 64 + n * 32 + colq;
      const float bv = bias[col];
      float* cp = C + (size_t)rowb * N + col;
#pragma unroll
      for (int q = 0; q < 16; ++q) {
        const int dr = (q & 3) + 8 * (q >> 2);
        cp[(size_t)dr * N] = acc[m][n][q] + bv;
      }
    }
  }
}

// ---------------- fallback: slow but correct ----------------
__global__ void gemm_naive_kernel(const float* __restrict__ x, const float* __restrict__ wgt,
                                  const float* __restrict__ bias, float* __restrict__ out,
                                  int M, int N, int K) {
  long long idx = (long long)blockIdx.x * blockDim.x + threadIdx.x;
  if (idx >= (long long)M * N) return;
  int o = (int)(idx % N);
  int m = (int)(idx / N);
  const float* xr = x + (size_t)m * K;
  const float* wr = wgt + (size_t)o * K;
  float s = 0.f;
  for (int i = 0; i < K; ++i) {
    float wv = wr[i];
    float t = (wv > 0.05f) ? 1.f : ((wv < -0.05f) ? -1.f : 0.f);
    s = fmaf(xr[i], t, s);
  }
  out[idx] = s + bias[o];
}

extern "C" void kernel_launch(void* const* d_in, const int* in_sizes, int n_in,
                              void* d_out, int out_size, void* d_ws, size_t ws_size,
                              hipStream_t stream) {
  const float* x    = (const float*)d_in[0];
  const float* wgt  = (const float*)d_in[1];
  const float* bias = (const float*)d_in[2];
  float* out = (float*)d_out;

  const int N = in_sizes[2];                 // out features
  const int K = in_sizes[1] / N;             // in features
  const int M = in_sizes[0] / K;             // batch rows

  const size_t need = (size_t)M * K * 2 + (size_t)N * K / 4;  // bf16 A + 2-bit B
  if (ws_size >= need && (M % 256 == 0) && (N % 256 == 0) && (K % 64 == 0) && K >= 256) {
    u16* xb = (u16*)d_ws;
    u16* wb = xb + (size_t)M * K;
    const int Kt = K / 64;
    cvt_x_perm<<<(M / 256) * Kt, 256, 0, stream>>>(x, xb, K);
    quant_w_pack2<<<(N / 256) * Kt, 512, 0, stream>>>(wgt, wb, K);
    const int grid = (M / 256) * (N / 256);
    gemm_bin_pk2<<<grid, 512, 0, stream>>>(xb, wb, bias, out, M, N, K);
  } else {
    const long long total = (long long)M * N;
    gemm_naive_kernel<<<(unsigned)((total + 255) / 256), 256, 0, stream>>>(x, wgt, bias, out, M, N, K);
  }
}

// Round 18
// 293.683 us; speedup vs baseline: 1.2313x; 1.2313x over previous
//
#include <hip/hip_runtime.h>

typedef float floatx16 __attribute__((ext_vector_type(16)));
typedef __bf16 bf16x8 __attribute__((ext_vector_type(8)));
using u16 = unsigned short;
using u32 = unsigned int;

#define GLOBAL_AS __attribute__((address_space(1)))
#define LDS_AS    __attribute__((address_space(3)))

__device__ __forceinline__ u32 rne_bf16(float f) {
  u32 u = __float_as_uint(f);
  return (u + 0x7FFFu + ((u >> 16) & 1u)) >> 16;  // RNE
}

// ---- A: fp32 -> bf16, permuted into per-K32-step frag-linear image (256-row panels) ----
// Step s (K32): 8192 u16 at panel + s*8192; idx = gi*1024 + ks*512 + l*8 + e,
// row = gi*32 + (l&31), k = s*32 + ks*16 + (l>>5)*8 + e  (32x32x16 operand layout).
__global__ __launch_bounds__(256) void cvt_x_perm32(const float* __restrict__ x,
                                                    u16* __restrict__ xb, int K) {
  __shared__ u16 sm[16384];
  const int tid = threadIdx.x;
  const int Kt = K >> 6;
  const int pn = blockIdx.x / Kt, tt = blockIdx.x % Kt;
  const float* src = x + (size_t)pn * 256 * K + tt * 64;
#pragma unroll
  for (int j = 0; j < 16; ++j) {
    const int fc = j * 256 + tid;
    const int row = fc >> 4, kl4 = fc & 15;
    const float4 v = *(const float4*)(src + (size_t)row * K + kl4 * 4);
    uint2 o;
    o.x = rne_bf16(v.x) | (rne_bf16(v.y) << 16);
    o.y = rne_bf16(v.z) | (rne_bf16(v.w) << 16);
    const int off = ((kl4 >> 3) & 1) * 8192 + (row >> 5) * 1024 +
                    ((kl4 >> 2) & 1) * 512 +
                    ((row & 31) + 32 * ((kl4 >> 1) & 1)) * 8 + (kl4 & 1) * 4;
    *(uint2*)(sm + off) = o;
  }
  __syncthreads();
  u16* dst = xb + (size_t)pn * 256 * K + (size_t)tt * 16384;
#pragma unroll
  for (int j = 0; j < 8; ++j) {
    const int o = (j * 256 + tid) * 8;
    *(uint4*)(dst + o) = *(const uint4*)(sm + o);
  }
}

// ---- B: fp32 -> ternary bf16, per-K32-step frag-linear image (128-row panels) ----
// Step s: 4096 u16 at panel + s*4096; idx = ni*1024 + ks*512 + l*8 + e,
// n = ni*32 + (l&31), k = s*32 + ks*16 + (l>>5)*8 + e.
__global__ __launch_bounds__(256) void quant_w_perm32(const float* __restrict__ w,
                                                      u16* __restrict__ wb, int K) {
  __shared__ u16 sm[8192];
  const int tid = threadIdx.x;
  const int Kt = K >> 6;
  const int bnp = blockIdx.x / Kt, tt = blockIdx.x % Kt;
  const float* src = w + (size_t)bnp * 128 * K + tt * 64;
#pragma unroll
  for (int j = 0; j < 8; ++j) {
    const int fc = j * 256 + tid;
    const int row = fc >> 4, kl4 = fc & 15;   // row 0..127
    const float4 v = *(const float4*)(src + (size_t)row * K + kl4 * 4);
    float vv[4] = {v.x, v.y, v.z, v.w};
    u32 r[4];
#pragma unroll
    for (int e = 0; e < 4; ++e)
      r[e] = (vv[e] > 0.05f) ? 0x3F80u : ((vv[e] < -0.05f) ? 0xBF80u : 0u);
    uint2 o;
    o.x = r[0] | (r[1] << 16);
    o.y = r[2] | (r[3] << 16);
    const int off = ((kl4 >> 3) & 1) * 4096 + (row >> 5) * 1024 +
                    ((kl4 >> 2) & 1) * 512 +
                    ((row & 31) + 32 * ((kl4 >> 1) & 1)) * 8 + (kl4 & 1) * 4;
    *(uint2*)(sm + off) = o;
  }
  __syncthreads();
  u16* dst = wb + (size_t)bnp * 128 * K + (size_t)tt * 8192;
#pragma unroll
  for (int j = 0; j < 4; ++j) {
    const int o = (j * 256 + tid) * 8;
    *(uint4*)(dst + o) = *(const uint4*)(sm + o);
  }
}

// ---------------- 256x128 BK=32 GEMM, ring-3 LDS (72KB), 2 blocks/CU (4 waves/SIMD) ----------------
// Clean TLP test (R8 geometry, staging bugs fixed): 8 waves (4x2) of 64x64,
// mfma 32x32x16, acc[2][2] floatx16 = 64 regs -> <=128 VGPR (launch_bounds 512,4).
// LDS ring-3 x 12288 u16 (A 8192 | B 4096) = 72KB -> 2 resident blocks/CU in
// independent barrier domains: one block's read/barrier windows hide under the
// other's MFMAs. Staging is LINEAR from pre-permuted global (coalesced, R9 fix).
// Per step s: stage(s+2)->slot2 (3 gloads); 8 ds_read_b128 (ks0 group then ks1);
// lgkm(4)->4 MFMA; lgkm(0)->4 MFMA; vmcnt(3) [drains stage(s+1)]; barrier.
__global__ __launch_bounds__(512, 4) void gemm_bin_tlp(
    const u16* __restrict__ Ap, const u16* __restrict__ Bp,
    const float* __restrict__ bias, float* __restrict__ C,
    int M, int N, int K) {
  __shared__ u16 lds[36864];  // 3 x 12288 u16 = 72 KiB

  const int tid = threadIdx.x;
  const int w = tid >> 6, l = tid & 63;
  const int wr = w >> 1, wc = w & 1;   // 4x2 wave grid, 64x64 each

  const int nbn = N >> 7;
  int wg = blockIdx.x;
  const int nwg = gridDim.x;
  if ((nwg & 7) == 0) wg = (wg & 7) * (nwg >> 3) + (wg >> 3);  // XCD swizzle (bijective)
  const int bm = wg / nbn, bn = wg % nbn;

  const int S = K >> 5;  // K32 steps

  const u16* const Apanel = Ap + (size_t)bm * 256 * K + tid * 8;  // + s*8192 + c*4096
  const u16* const Bpanel = Bp + (size_t)bn * 128 * K + tid * 8;  // + s*4096

  const u16* const afp0 = lds + wr * 2048 + l * 8;         // + slot*12288 + mg*1024 + ks*512
  const u16* const bfp0 = lds + 8192 + wc * 2048 + l * 8;  // + slot*12288 + ng*1024 + ks*512

  floatx16 acc[2][2] = {};
  bf16x8 af[4], bf[4];

#define GLOAD(gptr, u16off)                                                    \
  __builtin_amdgcn_global_load_lds((const GLOBAL_AS void*)(gptr),              \
                                   (LDS_AS void*)(lds + (u16off)), 16, 0, 0)
#define STAGE(ss, slot_)                                                       \
  {                                                                            \
    GLOAD(Apanel + (size_t)(ss) * 8192,        (slot_) * 12288 + tid * 8);     \
    GLOAD(Apanel + (size_t)(ss) * 8192 + 4096, (slot_) * 12288 + 4096 + tid * 8); \
    GLOAD(Bpanel + (size_t)(ss) * 4096,        (slot_) * 12288 + 8192 + tid * 8); \
  }

  // prologue: stage steps 0,1 -> slots 0,1
  STAGE(0, 0)
  STAGE(1, 1)
  asm volatile("s_waitcnt vmcnt(3)" ::: "memory");  // slot 0 landed
  __builtin_amdgcn_s_barrier();

  int slot = 0, slot2 = 2;
  for (int s = 0; s < S; ++s) {
    if (s + 2 < S) STAGE(s + 2, slot2)

    const u16* afp = afp0 + slot * 12288;
    const u16* bfp = bfp0 + slot * 12288;
    // ks=0 group first (4 reads), then ks=1 group (4 reads)
    af[0] = *(const bf16x8*)(afp + 0);
    af[1] = *(const bf16x8*)(afp + 1024);
    bf[0] = *(const bf16x8*)(bfp + 0);
    bf[1] = *(const bf16x8*)(bfp + 1024);
    af[2] = *(const bf16x8*)(afp + 512);
    af[3] = *(const bf16x8*)(afp + 1024 + 512);
    bf[2] = *(const bf16x8*)(bfp + 512);
    bf[3] = *(const bf16x8*)(bfp + 1024 + 512);

    asm volatile("s_waitcnt lgkmcnt(4)" ::: "memory");  // ks0 group landed
    __builtin_amdgcn_sched_barrier(0);
    __builtin_amdgcn_s_setprio(1);
    acc[0][0] = __builtin_amdgcn_mfma_f32_32x32x16_bf16(af[0], bf[0], acc[0][0], 0, 0, 0);
    acc[0][1] = __builtin_amdgcn_mfma_f32_32x32x16_bf16(af[0], bf[1], acc[0][1], 0, 0, 0);
    acc[1][0] = __builtin_amdgcn_mfma_f32_32x32x16_bf16(af[1], bf[0], acc[1][0], 0, 0, 0);
    acc[1][1] = __builtin_amdgcn_mfma_f32_32x32x16_bf16(af[1], bf[1], acc[1][1], 0, 0, 0);
    __builtin_amdgcn_s_setprio(0);

    asm volatile("s_waitcnt lgkmcnt(0)" ::: "memory");  // ks1 group landed
    __builtin_amdgcn_sched_barrier(0);
    __builtin_amdgcn_s_setprio(1);
    acc[0][0] = __builtin_amdgcn_mfma_f32_32x32x16_bf16(af[2], bf[2], acc[0][0], 0, 0, 0);
    acc[0][1] = __builtin_amdgcn_mfma_f32_32x32x16_bf16(af[2], bf[3], acc[0][1], 0, 0, 0);
    acc[1][0] = __builtin_amdgcn_mfma_f32_32x32x16_bf16(af[3], bf[2], acc[1][0], 0, 0, 0);
    acc[1][1] = __builtin_amdgcn_mfma_f32_32x32x16_bf16(af[3], bf[3], acc[1][1], 0, 0, 0);
    __builtin_amdgcn_s_setprio(0);

    if (s + 1 < S) {
      if (s + 2 < S) asm volatile("s_waitcnt vmcnt(3)" ::: "memory");  // drain stage(s+1)
      else           asm volatile("s_waitcnt vmcnt(0)" ::: "memory");
      __builtin_amdgcn_s_barrier();
    }
    slot = (slot == 2) ? 0 : slot + 1;
    slot2 = (slot2 == 2) ? 0 : slot2 + 1;
  }
#undef STAGE
#undef GLOAD

  // ---- epilogue: C/D col=l&31, row=(q&3)+8*(q>>2)+4*(l>>5) (m74/m101-verified) ----
  const int colq = l & 31;
  const int hi4 = (l >> 5) * 4;
#pragma unroll
  for (int mg = 0; mg < 2; ++mg) {
    const int rowb = bm * 256 + wr * 64 + mg * 32 + hi4;
#pragma unroll
    for (int ng = 0; ng < 2; ++ng) {
      const int col = bn * 128 + wc * 64 + ng * 32 + colq;
      const float bv = bias[col];
      float* cp = C + (size_t)rowb * N + col;
#pragma unroll
      for (int q = 0; q < 16; ++q) {
        const int dr = (q & 3) + 8 * (q >> 2);
        cp[(size_t)dr * N] = acc[mg][ng][q] + bv;
      }
    }
  }
}

// ---------------- fallback: slow but correct ----------------
__global__ void gemm_naive_kernel(const float* __restrict__ x, const float* __restrict__ wgt,
                                  const float* __restrict__ bias, float* __restrict__ out,
                                  int M, int N, int K) {
  long long idx = (long long)blockIdx.x * blockDim.x + threadIdx.x;
  if (idx >= (long long)M * N) return;
  int o = (int)(idx % N);
  int m = (int)(idx / N);
  const float* xr = x + (size_t)m * K;
  const float* wr = wgt + (size_t)o * K;
  float s = 0.f;
  for (int i = 0; i < K; ++i) {
    float wv = wr[i];
    float t = (wv > 0.05f) ? 1.f : ((wv < -0.05f) ? -1.f : 0.f);
    s = fmaf(xr[i], t, s);
  }
  out[idx] = s + bias[o];
}

extern "C" void kernel_launch(void* const* d_in, const int* in_sizes, int n_in,
                              void* d_out, int out_size, void* d_ws, size_t ws_size,
                              hipStream_t stream) {
  const float* x    = (const float*)d_in[0];
  const float* wgt  = (const float*)d_in[1];
  const float* bias = (const float*)d_in[2];
  float* out = (float*)d_out;

  const int N = in_sizes[2];                 // out features
  const int K = in_sizes[1] / N;             // in features
  const int M = in_sizes[0] / K;             // batch rows

  const size_t need = ((size_t)M * K + (size_t)N * K) * sizeof(u16);
  if (ws_size >= need && (M % 256 == 0) && (N % 128 == 0) && (K % 64 == 0) && K >= 128) {
    u16* xb = (u16*)d_ws;
    u16* wb = xb + (size_t)M * K;
    const int Kt = K / 64;
    cvt_x_perm32<<<(M / 256) * Kt, 256, 0, stream>>>(x, xb, K);
    quant_w_perm32<<<(N / 128) * Kt, 256, 0, stream>>>(wgt, wb, K);
    const int grid = (M / 256) * (N / 128);
    gemm_bin_tlp<<<grid, 512, 0, stream>>>(xb, wb, bias, out, M, N, K);
  } else {
    const long long total = (long long)M * N;
    gemm_naive_kernel<<<(unsigned)((total + 255) / 256), 256, 0, stream>>>(x, wgt, bias, out, M, N, K);
  }
}

// Round 19
// 286.103 us; speedup vs baseline: 1.2639x; 1.0265x over previous
//
#include <hip/hip_runtime.h>

typedef float floatx16 __attribute__((ext_vector_type(16)));
typedef __bf16 bf16x8 __attribute__((ext_vector_type(8)));
using u16 = unsigned short;
using u32 = unsigned int;

#define GLOBAL_AS __attribute__((address_space(1)))
#define LDS_AS    __attribute__((address_space(3)))

__device__ __forceinline__ u32 rne_bf16(float f) {
  u32 u = __float_as_uint(f);
  return (u + 0x7FFFu + ((u >> 16) & 1u)) >> 16;  // RNE
}

// ---------------- A: fp32 -> bf16, tile-permuted for 32x32x16 frags (R10) ----------------
__global__ __launch_bounds__(256) void cvt_x_perm(const float* __restrict__ x,
                                                  u16* __restrict__ xb, int K) {
  __shared__ u16 sm[16384];
  const int tid = threadIdx.x;
  const int Kt = K >> 6;
  const int pn = blockIdx.x / Kt, tt = blockIdx.x % Kt;
  const float* src = x + (size_t)pn * 256 * K + tt * 64;
#pragma unroll
  for (int j = 0; j < 16; ++j) {
    const int fc = j * 256 + tid;
    const int row = fc >> 4, kl4 = fc & 15;
    const float4 v = *(const float4*)(src + (size_t)row * K + kl4 * 4);
    uint2 o;
    o.x = rne_bf16(v.x) | (rne_bf16(v.y) << 16);
    o.y = rne_bf16(v.z) | (rne_bf16(v.w) << 16);
    const int gi = row >> 5, rowin = row & 31;
    const int ks = kl4 >> 2;
    const int lane = rowin + 32 * ((kl4 >> 1) & 1);
    const int e4 = (kl4 & 1) * 4;
    *(uint2*)(sm + gi * 2048 + ks * 512 + lane * 8 + e4) = o;
  }
  __syncthreads();
  u16* dst = xb + (size_t)pn * 256 * K + (size_t)tt * 16384;
#pragma unroll
  for (int j = 0; j < 8; ++j) {
    const int o = (j * 256 + tid) * 8;
    *(uint4*)(dst + o) = *(const uint4*)(sm + o);
  }
}

// ---------------- B: fp32 -> ternary bf16, same tile-permuted layout ----------------
__global__ __launch_bounds__(256) void quant_w_perm(const float* __restrict__ w,
                                                    u16* __restrict__ wb, int K) {
  __shared__ u16 sm[16384];
  const int tid = threadIdx.x;
  const int Kt = K >> 6;
  const int pn = blockIdx.x / Kt, tt = blockIdx.x % Kt;
  const float* src = w + (size_t)pn * 256 * K + tt * 64;
#pragma unroll
  for (int j = 0; j < 16; ++j) {
    const int fc = j * 256 + tid;
    const int row = fc >> 4, kl4 = fc & 15;
    const float4 v = *(const float4*)(src + (size_t)row * K + kl4 * 4);
    float vv[4] = {v.x, v.y, v.z, v.w};
    u32 r[4];
#pragma unroll
    for (int e = 0; e < 4; ++e)
      r[e] = (vv[e] > 0.05f) ? 0x3F80u : ((vv[e] < -0.05f) ? 0xBF80u : 0u);
    uint2 o;
    o.x = r[0] | (r[1] << 16);
    o.y = r[2] | (r[3] << 16);
    const int gi = row >> 5, rowin = row & 31;
    const int ks = kl4 >> 2;
    const int lane = rowin + 32 * ((kl4 >> 1) & 1);
    const int e4 = (kl4 & 1) * 4;
    *(uint2*)(sm + gi * 2048 + ks * 512 + lane * 8 + e4) = o;
  }
  __syncthreads();
  u16* dst = wb + (size_t)pn * 256 * K + (size_t)tt * 16384;
#pragma unroll
  for (int j = 0; j < 8; ++j) {
    const int o = (j * 256 + tid) * 8;
    *(uint4*)(dst + o) = *(const uint4*)(sm + o);
  }
}

// ---------------- 256x256 BK=64 GEMM, mfma 32x32x16, m201 vmcnt discipline (R11) ----------------
// Stage calendar (2 gloads/phase, chunk-death-safe):
//   P1(t): A c1,c3 of (t+1) -> buf(t+1)   [died at P3(t-1)]
//   P2(t): A c0,c2 of (t+2) -> buf(t)     [died at P1(t)]
//   P3(t): B c0,c1 of (t+2) -> buf(t)     [died at P2(t)]
//   P4(t): B c2,c3 of (t+2) -> buf(t)     [died at P2(t)]
// Single counted wait per tile: end-P4 vmcnt(6) -- newest 6 = tile(t+2)'s loads,
// so ALL of tile t+1 has landed (RAW); each overwrite issues after the barrier
// closing its last reader phase (WAR).
__global__ __launch_bounds__(512, 2) void gemm_bin_m201d(
    const u16* __restrict__ Ap, const u16* __restrict__ Bp,
    const float* __restrict__ bias, float* __restrict__ C,
    int M, int N, int K) {
  __shared__ u16 lds[65536];  // 2 buf x (A 16384 | B 16384) u16

  const int tid = threadIdx.x;
  const int w = tid >> 6, l = tid & 63;
  const int wr = w >> 2, wc = w & 3;

  const int nbn = N >> 8;
  int wg = blockIdx.x;
  const int nwg = gridDim.x;
  if ((nwg & 7) == 0) wg = (wg & 7) * (nwg >> 3) + (wg >> 3);  // XCD swizzle (bijective)
  const int bm = wg / nbn, bn = wg % nbn;

  const int T = K >> 6;

  const u16* const Abase = Ap + (size_t)bm * ((size_t)K << 8) + tid * 8;
  const u16* const Bbase = Bp + (size_t)bn * ((size_t)K << 8) + tid * 8;

  const u16* const afp0 = lds + wr * 8192 + l * 8;
  const u16* const bfp0 = lds + 16384 + wc * 4096 + l * 8;

  floatx16 acc[4][2] = {};
  bf16x8 af[8], bflo[4], bfhi[4];

#define GLOAD(gptr, u16off)                                                    \
  __builtin_amdgcn_global_load_lds((const GLOBAL_AS void*)(gptr),              \
                                   (LDS_AS void*)(lds + (u16off)), 16, 0, 0)
#define BARRIER __builtin_amdgcn_s_barrier()
#define LGKM0  do { asm volatile("s_waitcnt lgkmcnt(0)" ::: "memory");         \
                    __builtin_amdgcn_sched_barrier(0); } while (0)

  // prologue: tile0 (A c0,c2 | B q0..q3 | A c1,c3) then tile1 (A c0,c2 | B q0..q3)
  GLOAD(Abase + 0 * 4096,      0 + tid * 8);
  GLOAD(Abase + 2 * 4096,   8192 + tid * 8);
  GLOAD(Bbase + 0 * 4096,  16384 + tid * 8);
  GLOAD(Bbase + 1 * 4096,  20480 + tid * 8);
  GLOAD(Bbase + 2 * 4096,  24576 + tid * 8);
  GLOAD(Bbase + 3 * 4096,  28672 + tid * 8);
  GLOAD(Abase + 1 * 4096,   4096 + tid * 8);
  GLOAD(Abase + 3 * 4096,  12288 + tid * 8);
  if (T > 1) {
    GLOAD(Abase + 16384 + 0 * 4096, 32768 + 0 + tid * 8);
    GLOAD(Abase + 16384 + 2 * 4096, 32768 + 8192 + tid * 8);
    GLOAD(Bbase + 16384 + 0 * 4096, 32768 + 16384 + tid * 8);
    GLOAD(Bbase + 16384 + 1 * 4096, 32768 + 20480 + tid * 8);
    GLOAD(Bbase + 16384 + 2 * 4096, 32768 + 24576 + tid * 8);
    GLOAD(Bbase + 16384 + 3 * 4096, 32768 + 28672 + tid * 8);
    asm volatile("s_waitcnt vmcnt(6)" ::: "memory");  // tile0 fully landed
  } else {
    asm volatile("s_waitcnt vmcnt(0)" ::: "memory");
  }
  BARRIER;

  for (int t = 0; t < T; ++t) {
    const int bufc = (t & 1) << 15;
    const int bufo = bufc ^ 32768;
    const bool st1 = (t + 1 < T);
    const bool st2 = (t + 2 < T);
    const size_t tn1 = (size_t)(t + 1) * 16384;
    const size_t tn2 = (size_t)(t + 2) * 16384;

    const u16* afp = afp0 + bufc;
    const u16* bfp = bfp0 + bufc;

    // ---- P1: af m0,m1 (8) + bflo (4); stage A c1,c3 (t+1)->bufo; MFMA (m0,m1)x(n0) ----
#pragma unroll
    for (int m = 0; m < 2; ++m)
#pragma unroll
      for (int ks = 0; ks < 4; ++ks)
        af[m * 4 + ks] = *(const bf16x8*)(afp + m * 2048 + ks * 512);
#pragma unroll
    for (int ks = 0; ks < 4; ++ks) bflo[ks] = *(const bf16x8*)(bfp + ks * 512);
    if (st1) {
      GLOAD(Abase + tn1 + 1 * 4096, bufo + 4096 + tid * 8);
      GLOAD(Abase + tn1 + 3 * 4096, bufo + 12288 + tid * 8);
    }
    asm volatile("s_waitcnt lgkmcnt(8)" ::: "memory");
    BARRIER;
    LGKM0;
    __builtin_amdgcn_s_setprio(1);
#pragma unroll
    for (int ks = 0; ks < 4; ++ks)
#pragma unroll
      for (int m = 0; m < 2; ++m)
        acc[m][0] = __builtin_amdgcn_mfma_f32_32x32x16_bf16(
            af[m * 4 + ks], bflo[ks], acc[m][0], 0, 0, 0);
    __builtin_amdgcn_s_setprio(0);
    BARRIER;

    // ---- P2: bfhi (4); stage A c0,c2 (t+2)->bufc; MFMA (m0,m1)x(n1) ----
#pragma unroll
    for (int ks = 0; ks < 4; ++ks) bfhi[ks] = *(const bf16x8*)(bfp + 2048 + ks * 512);
    if (st2) {
      GLOAD(Abase + tn2 + 0 * 4096, bufc + 0 + tid * 8);
      GLOAD(Abase + tn2 + 2 * 4096, bufc + 8192 + tid * 8);
    }
    BARRIER;
    LGKM0;
    __builtin_amdgcn_s_setprio(1);
#pragma unroll
    for (int ks = 0; ks < 4; ++ks)
#pragma unroll
      for (int m = 0; m < 2; ++m)
        acc[m][1] = __builtin_amdgcn_mfma_f32_32x32x16_bf16(
            af[m * 4 + ks], bfhi[ks], acc[m][1], 0, 0, 0);
    __builtin_amdgcn_s_setprio(0);
    BARRIER;

    // ---- P3: af m2,m3 (8); stage B c0,c1 (t+2)->bufc; MFMA (m2,m3)x(n0) ----
#pragma unroll
    for (int m = 0; m < 2; ++m)
#pragma unroll
      for (int ks = 0; ks < 4; ++ks)
        af[m * 4 + ks] = *(const bf16x8*)(afp + 4096 + m * 2048 + ks * 512);
    if (st2) {
      GLOAD(Bbase + tn2 + 0 * 4096, bufc + 16384 + tid * 8);
      GLOAD(Bbase + tn2 + 1 * 4096, bufc + 20480 + tid * 8);
    }
    asm volatile("s_waitcnt lgkmcnt(4)" ::: "memory");
    BARRIER;
    LGKM0;
    __builtin_amdgcn_s_setprio(1);
#pragma unroll
    for (int ks = 0; ks < 4; ++ks)
#pragma unroll
      for (int m = 0; m < 2; ++m)
        acc[2 + m][0] = __builtin_amdgcn_mfma_f32_32x32x16_bf16(
            af[m * 4 + ks], bflo[ks], acc[2 + m][0], 0, 0, 0);
    __builtin_amdgcn_s_setprio(0);
    BARRIER;

    // ---- P4: stage B c2,c3 (t+2)->bufc; MFMA (m2,m3)x(n1); vmcnt(6); barrier ----
    if (st2) {
      GLOAD(Bbase + tn2 + 2 * 4096, bufc + 24576 + tid * 8);
      GLOAD(Bbase + tn2 + 3 * 4096, bufc + 28672 + tid * 8);
    }
    BARRIER;
    __builtin_amdgcn_s_setprio(1);
#pragma unroll
    for (int ks = 0; ks < 4; ++ks)
#pragma unroll
      for (int m = 0; m < 2; ++m)
        acc[2 + m][1] = __builtin_amdgcn_mfma_f32_32x32x16_bf16(
            af[m * 4 + ks], bfhi[ks], acc[2 + m][1], 0, 0, 0);
    __builtin_amdgcn_s_setprio(0);
    if (st2) asm volatile("s_waitcnt vmcnt(6)" ::: "memory");
    else     asm volatile("s_waitcnt vmcnt(0)" ::: "memory");
    BARRIER;
  }
#undef GLOAD
#undef BARRIER
#undef LGKM0

  // ---- epilogue: C/D col=l&31, row=(q&3)+8*(q>>2)+4*(l>>5) (m74/m101-verified) ----
  const int colq = l & 31;
  const int hi4 = (l >> 5) * 4;
#pragma unroll
  for (int m = 0; m < 4; ++m) {
    const int rowb = bm * 256 + wr * 128 + m * 32 + hi4;
#pragma unroll
    for (int n = 0; n < 2; ++n) {
      const int col = bn * 256 + wc * 64 + n * 32 + colq;
      const float bv = bias[col];
      float* cp = C + (size_t)rowb * N + col;
#pragma unroll
      for (int q = 0; q < 16; ++q) {
        const int dr = (q & 3) + 8 * (q >> 2);
        cp[(size_t)dr * N] = acc[m][n][q] + bv;
      }
    }
  }
}

// ---------------- fallback: slow but correct ----------------
__global__ void gemm_naive_kernel(const float* __restrict__ x, const float* __restrict__ wgt,
                                  const float* __restrict__ bias, float* __restrict__ out,
                                  int M, int N, int K) {
  long long idx = (long long)blockIdx.x * blockDim.x + threadIdx.x;
  if (idx >= (long long)M * N) return;
  int o = (int)(idx % N);
  int m = (int)(idx / N);
  const float* xr = x + (size_t)m * K;
  const float* wr = wgt + (size_t)o * K;
  float s = 0.f;
  for (int i = 0; i < K; ++i) {
    float wv = wr[i];
    float t = (wv > 0.05f) ? 1.f : ((wv < -0.05f) ? -1.f : 0.f);
    s = fmaf(xr[i], t, s);
  }
  out[idx] = s + bias[o];
}

extern "C" void kernel_launch(void* const* d_in, const int* in_sizes, int n_in,
                              void* d_out, int out_size, void* d_ws, size_t ws_size,
                              hipStream_t stream) {
  const float* x    = (const float*)d_in[0];
  const float* wgt  = (const float*)d_in[1];
  const float* bias = (const float*)d_in[2];
  float* out = (float*)d_out;

  const int N = in_sizes[2];                 // out features
  const int K = in_sizes[1] / N;             // in features
  const int M = in_sizes[0] / K;             // batch rows

  const size_t need = ((size_t)M * K + (size_t)N * K) * sizeof(u16);
  if (ws_size >= need && (M % 256 == 0) && (N % 256 == 0) && (K % 64 == 0) && K >= 192) {
    u16* xb = (u16*)d_ws;
    u16* wb = xb + (size_t)M * K;
    const int Kt = K / 64;
    cvt_x_perm<<<(M / 256) * Kt, 256, 0, stream>>>(x, xb, K);
    quant_w_perm<<<(N / 256) * Kt, 256, 0, stream>>>(wgt, wb, K);
    const int grid = (M / 256) * (N / 256);
    gemm_bin_m201d<<<grid, 512, 0, stream>>>(xb, wb, bias, out, M, N, K);
  } else {
    const long long total = (long long)M * N;
    gemm_naive_kernel<<<(unsigned)((total + 255) / 256), 256, 0, stream>>>(x, wgt, bias, out, M, N, K);
  }
}